// Round 1
// 7110.651 us; speedup vs baseline: 1.1545x; 1.1545x over previous
//
#include <hip/hip_runtime.h>

#define TT 512
#define BSZ 64
#define DD 512
#define HH 512
#define NGROUP 4
#define GBLK 64        // blocks per group
#define GBATCH 16      // batches per group

struct Params {
    const float* X;
    const float* Wx[4];   // W_xi, W_xf, W_xo, W_xc   [D][H] row-major
    const float* Wh[4];   // W_hi, W_hf, W_ho, W_hc   [H][H] row-major
    const float* bias[4]; // b_i, b_f, b_o, b_c       [H]
    float* Y;             // [B][T][H]
    float* hbuf;          // ws: 2 * B * H floats (double buffer)
    unsigned int* ctr;    // ws: NGROUP counters, 64-uint padded
};

__device__ __forceinline__ float fast_sigmoid(float x) {
    return 1.0f / (1.0f + __expf(-x));
}

__device__ __forceinline__ float fast_tanh(float x) {
    float ax = fabsf(x);
    float e  = __expf(-2.0f * ax);
    float r  = (1.0f - e) / (1.0f + e);
    return copysignf(r, x);
}

// hbuf/ctr are accessed ONLY via cache-bypassing (agent-scope relaxed) ops in
// the main kernel, so the init writes must also be write-through: a normal
// cached store would leave the zeros dirty in one XCD's L2, invisible to
// bypass reads from other XCDs.
__global__ void init_ws(float* hbuf, unsigned int* ctr) {
    int i = blockIdx.x * blockDim.x + threadIdx.x;
    int stride = gridDim.x * blockDim.x;
    for (int k = i; k < 2 * BSZ * HH; k += stride)
        __hip_atomic_store(&hbuf[k], 0.0f, __ATOMIC_RELAXED, __HIP_MEMORY_SCOPE_AGENT);
    if (i < 8 * 64)
        __hip_atomic_store(&ctr[i], 0u, __ATOMIC_RELAXED, __HIP_MEMORY_SCOPE_AGENT);
}

// Persistent LSTM. 256 blocks x 256 threads. 146.5 KB LDS -> 1 block/CU.
// 4 groups x 64 blocks; group g owns batches [16g, 16g+16).
// Block k owns hidden units [8k, 8k+8) -> 32 gate columns.
// Thread (c = tid&31, s = tid>>5): col c (gate=c>>3), K-slice [64s, 64s+64).
//
// SPILL HISTORY: R2 (256 reg w-floats) spilled; R3 (128) spilled; R4 (64 regs
// + LDS wx but FULL 16x16 unroll of both FMA loops = 2x256 hoisted ds_read_b128
// live ranges) ALSO spilled -> 77 GB scratch writes. Root cause is
// scheduler-driven live-range blowup, so this version caps it:
//   - x-loop: #pragma unroll 1 (weights from LDS, no const-index need)
//   - h-loop: full unroll (wh4[] reg array NEEDS constant indices) but
//     sched_barrier(0) after each K-chunk -> <=16 b128 loads in flight.
//
// COHERENCE (this round's change): the previous version used
// RELEASE fetch_add (-> buffer_wbl2, L2 writeback) + ACQUIRE fence
// (-> buffer_inv, invalidates L1+L2) EVERY step in EVERY block. That put
// ~2 cache-maintenance ops per CU per step on the critical path and nuked
// the per-XCD L2 every 16us (FETCH_SIZE was 8.5x the X tensor).
// Now: h exchange is Infinity-Cache-coherent with ZERO fences.
//   producer: __hip_atomic_store(h, RELAXED, AGENT)  -> write-through (sc0 sc1)
//   __syncthreads() drains vmcnt (stores complete at coherence point)
//   tid0:     fetch_add RELAXED (no wbl2)
//   consumer: tid0 relaxed spin (bypass load sees IF), NO acquire fence,
//             h staged via relaxed agent loads (bypass L1/L2, read from IF).
// X / Y / weights keep normal cached access and the L2 now survives steps.
__global__ __launch_bounds__(256, 1) void lstm_persist(Params p) {
    __shared__ float wx_lds[DD * 33];        // 66 KB: W_x slice, [k][c] pad-33
    __shared__ float hs[GBATCH * HH];        // 32 KB: h_{t-1}, 16 batches
    __shared__ float xs[GBATCH * DD];        // 32 KB: x_t, 16 batches
    __shared__ float part[GBATCH * 8 * 33];  // 16.9 KB: partials [bb][s][33(c)]

    const int bid  = blockIdx.x;
    const int g    = bid >> 6;             // group 0..3
    const int k    = bid & 63;             // block in group
    const int tid  = threadIdx.x;
    const int c    = tid & 31;             // col 0..31
    const int s    = tid >> 5;             // K-slice 0..7
    const int gate = c >> 3;
    const int jcol = k * 8 + (c & 7);      // weight-matrix column
    const int b0   = g * GBATCH;
    const int kb   = s * 64;               // K-slice start

    // ---- one-time: W_x slice (32 cols x 512 rows) into LDS, [k][c] ----
    for (int idx = tid; idx < 32 * DD; idx += 256) {
        int cc = idx & 31;
        int kk = idx >> 5;
        int gg = cc >> 3;
        int jc = k * 8 + (cc & 7);
        wx_lds[kk * 33 + cc] = p.Wx[gg][kk * HH + jc];
    }

    // ---- one-time: W_h slice into registers (64 floats) ----
    const float* WhG = p.Wh[gate];
    float4 wh4[16];
#pragma unroll
    for (int i = 0; i < 16; ++i) {
        int kk = kb + i * 4;
        wh4[i] = make_float4(WhG[(kk + 0) * HH + jcol], WhG[(kk + 1) * HH + jcol],
                             WhG[(kk + 2) * HH + jcol], WhG[(kk + 3) * HH + jcol]);
    }

    // Cell-update thread state (threads 0..127): (batch bbu, unit jju)
    const int bbu = tid >> 3;              // 0..15
    const int jju = tid & 7;
    const int ju  = k * 8 + jju;
    float cst = 0.0f;
    float bI = 0.f, bF = 0.f, bO = 0.f, bC = 0.f;
    if (tid < 128) {
        bI = p.bias[0][ju];
        bF = p.bias[1][ju];
        bO = p.bias[2][ju];
        bC = p.bias[3][ju];
    }

    unsigned int* ctrp = p.ctr + g * 64;
    const float4* xsrc = (const float4*)p.X;
    float4* hs4 = (float4*)hs;
    float4* xs4 = (float4*)xs;

    __syncthreads();   // wx_lds ready

    for (int t = 0; t < TT; ++t) {
        // ---- 1. stage x_t (no cross-block dependency) ----
#pragma unroll
        for (int u = 0; u < 8; ++u) {
            int idx = tid + u * 256;           // 0..2047
            int b   = idx >> 7;                // 0..15
            int dd  = idx & 127;               // float4 within row
            xs4[b * 128 + dd] = xsrc[((size_t)(b0 + b) * TT + t) * 128 + dd];
        }
        __syncthreads();

        // ---- 2. x-projection FMAs, weights streamed from LDS.
        //      unroll 1: body = 4 ds_read_b32 + 16 ds_read_b128 + 64 FMA ----
        float acc[16];
#pragma unroll
        for (int bb = 0; bb < 16; ++bb) acc[bb] = 0.0f;
#pragma unroll 1
        for (int i4 = 0; i4 < 16; ++i4) {
            const int kk = kb + i4 * 4;
            const float w0 = wx_lds[(kk + 0) * 33 + c];
            const float w1 = wx_lds[(kk + 1) * 33 + c];
            const float w2 = wx_lds[(kk + 2) * 33 + c];
            const float w3 = wx_lds[(kk + 3) * 33 + c];
            const float4* xp = &xs4[s * 16 + i4];
#pragma unroll
            for (int bb = 0; bb < 16; ++bb) {
                float4 xv = xp[bb * 128];      // 32-lane broadcast
                float a = acc[bb];
                a = fmaf(xv.x, w0, a);
                a = fmaf(xv.y, w1, a);
                a = fmaf(xv.z, w2, a);
                a = fmaf(xv.w, w3, a);
                acc[bb] = a;
            }
            __builtin_amdgcn_sched_barrier(0);
        }

        // ---- 3. wait for h_{t-1}: tid0-only relaxed spin (bypass load reads
        //      the IF directly — no fence, no cache invalidation) ----
        if (tid == 0) {
            const unsigned int need = (unsigned int)(GBLK * t);
            while (__hip_atomic_load(ctrp, __ATOMIC_RELAXED, __HIP_MEMORY_SCOPE_AGENT) < need) {
                __builtin_amdgcn_s_sleep(2);
            }
        }
        __syncthreads();

        // ---- 4. stage h_{t-1}: cache-bypassing (IF-coherent) loads,
        //      register-batched so all 32 loads are in flight at once ----
        {
            const float* hsrc = p.hbuf + (size_t)(t & 1) * BSZ * HH;
            float tmp[32];
#pragma unroll
            for (int u = 0; u < 32; ++u) {
                int idx = tid + u * 256;       // 0..8191
                int b   = idx >> 9;            // 0..15
                int d   = idx & 511;
                tmp[u] = __hip_atomic_load(&hsrc[(size_t)(b0 + b) * HH + d],
                                           __ATOMIC_RELAXED, __HIP_MEMORY_SCOPE_AGENT);
            }
#pragma unroll
            for (int u = 0; u < 32; ++u) {
                int idx = tid + u * 256;
                hs[idx] = tmp[u];
            }
        }
        __syncthreads();

        // ---- 5. recurrent FMAs, weights from registers. Full unroll is
        //      REQUIRED (wh4[] const indices); sched_barrier bounds the
        //      in-flight loads to one 16-b128 chunk ----
#pragma unroll
        for (int i4 = 0; i4 < 16; ++i4) {
            const float4 w = wh4[i4];
            const float4* hp = &hs4[s * 16 + i4];
#pragma unroll
            for (int bb = 0; bb < 16; ++bb) {
                float4 hv = hp[bb * 128];      // 32-lane broadcast
                float a = acc[bb];
                a = fmaf(hv.x, w.x, a);
                a = fmaf(hv.y, w.y, a);
                a = fmaf(hv.z, w.z, a);
                a = fmaf(hv.w, w.w, a);
                acc[bb] = a;
            }
            __builtin_amdgcn_sched_barrier(0);
        }

        // ---- 6. write partials (stride 33: conflict-free) ----
#pragma unroll
        for (int bb = 0; bb < 16; ++bb)
            part[(bb * 8 + s) * 33 + c] = acc[bb];
        __syncthreads();

        // ---- 7. cell update ----
        if (tid < 128) {
            float v0 = bI, v1 = bF, v2 = bO, v3 = bC;
#pragma unroll
            for (int ss = 0; ss < 8; ++ss) {
                const float* pr = &part[(bbu * 8 + ss) * 33];
                v0 += pr[0 * 8 + jju];
                v1 += pr[1 * 8 + jju];
                v2 += pr[2 * 8 + jju];
                v3 += pr[3 * 8 + jju];
            }
            float I  = fast_sigmoid(v0);
            float F  = fast_sigmoid(v1);
            float O  = fast_sigmoid(v2);
            float Cd = fast_tanh(v3);
            cst = fmaf(F, cst, I * Cd);
            float h = O * fast_tanh(cst);
            // write-through to the IF (coherence point) — no wbl2 needed later
            __hip_atomic_store(&p.hbuf[(size_t)((t + 1) & 1) * BSZ * HH + (b0 + bbu) * HH + ju],
                               h, __ATOMIC_RELAXED, __HIP_MEMORY_SCOPE_AGENT);
            p.Y[((size_t)(b0 + bbu) * TT + t) * HH + ju] = h;
        }
        __syncthreads();   // drains vmcnt: h stores complete at the IF

        // ---- 8. publish: tid0 RELAXED add (no wbl2; ordering comes from the
        //      vmcnt drain in the barrier above) ----
        if (tid == 0) {
            __hip_atomic_fetch_add(ctrp, 1u, __ATOMIC_RELAXED, __HIP_MEMORY_SCOPE_AGENT);
        }
    }
}

extern "C" void kernel_launch(void* const* d_in, const int* in_sizes, int n_in,
                              void* d_out, int out_size, void* d_ws, size_t ws_size,
                              hipStream_t stream) {
    Params p;
    p.X       = (const float*)d_in[0];
    p.Wx[0]   = (const float*)d_in[1];
    p.Wh[0]   = (const float*)d_in[2];
    p.bias[0] = (const float*)d_in[3];
    p.Wx[1]   = (const float*)d_in[4];
    p.Wh[1]   = (const float*)d_in[5];
    p.bias[1] = (const float*)d_in[6];
    p.Wx[2]   = (const float*)d_in[7];
    p.Wh[2]   = (const float*)d_in[8];
    p.bias[2] = (const float*)d_in[9];
    p.Wx[3]   = (const float*)d_in[10];
    p.Wh[3]   = (const float*)d_in[11];
    p.bias[3] = (const float*)d_in[12];
    p.Y       = (float*)d_out;
    p.hbuf    = (float*)d_ws;
    p.ctr     = (unsigned int*)((char*)d_ws + (size_t)2 * BSZ * HH * sizeof(float));

    // ws is poisoned 0xAA before every timed launch: zero h0 double-buffer + counters
    init_ws<<<64, 256, 0, stream>>>(p.hbuf, p.ctr);

    lstm_persist<<<dim3(256), dim3(256), 0, stream>>>(p);
}

// Round 2
// 4286.703 us; speedup vs baseline: 1.9150x; 1.6588x over previous
//
#include <hip/hip_runtime.h>

#define TT 512
#define BSZ 64
#define DD 512
#define HH 512
#define NGROUP 4
#define GBLK 64        // blocks per group
#define GBATCH 16      // batches per group
#define NT 512         // threads per block (8 waves -> 2 waves/SIMD)

struct Params {
    const float* X;
    const float* Wx[4];   // W_xi, W_xf, W_xo, W_xc   [D][H] row-major
    const float* Wh[4];   // W_hi, W_hf, W_ho, W_hc   [H][H] row-major
    const float* bias[4]; // b_i, b_f, b_o, b_c       [H]
    float* Y;             // [B][T][H]
    float* hbuf;          // ws: 2 * B * H floats (double buffer)
    unsigned int* ctr;    // ws: NGROUP counters, 64-uint padded
};

__device__ __forceinline__ float fast_sigmoid(float x) {
    return 1.0f / (1.0f + __expf(-x));
}

__device__ __forceinline__ float fast_tanh(float x) {
    float ax = fabsf(x);
    float e  = __expf(-2.0f * ax);
    float r  = (1.0f - e) / (1.0f + e);
    return copysignf(r, x);
}

// hbuf/ctr are accessed ONLY via cache-bypassing (agent-scope relaxed) ops in
// the main kernel, so the init writes must also be write-through.
__global__ void init_ws(float* hbuf, unsigned int* ctr) {
    int i = blockIdx.x * blockDim.x + threadIdx.x;
    int stride = gridDim.x * blockDim.x;
    for (int k = i; k < 2 * BSZ * HH; k += stride)
        __hip_atomic_store(&hbuf[k], 0.0f, __ATOMIC_RELAXED, __HIP_MEMORY_SCOPE_AGENT);
    if (i < 8 * 64)
        __hip_atomic_store(&ctr[i], 0u, __ATOMIC_RELAXED, __HIP_MEMORY_SCOPE_AGENT);
}

// Persistent LSTM. 256 blocks x 512 threads. 146.5 KB LDS -> 1 block/CU.
// R2 change: 512 threads (was 256). rocprof showed Occupancy 12.4% = exactly
// 1 wave/SIMD -> every lgkmcnt/vmcnt/barrier stall fully exposed (VALUBusy
// 33.7%, 9.5us/step of stall). 8 waves -> 2/SIMD gives each stall a partner
// wave. Per-thread K-slice halves to 32; the doubled partial-slice count is
// pair-combined IN-REGISTER via __shfl_xor(.,32) (pair lives in the two
// halves of the same wave) so the LDS footprint is unchanged (150016 B).
//
// XCD-pair swizzle: group g -> XCDs {2g,2g+1} (assumes round-robin bid%8
// dispatch; perf-only heuristic). FETCH_SIZE was 542 MB = every XCD
// re-fetching every group's x_t tile (4x32KB x 8 XCD x 512 steps); confining
// each group to 2 XCDs cuts X traffic ~4x.
//
// COHERENCE (unchanged from R1): h exchange is Infinity-Cache-coherent with
// ZERO fences. Producer: relaxed agent store (write-through). __syncthreads
// drains vmcnt. tid0 relaxed fetch_add publish; consumer tid0 relaxed spin,
// h staged via relaxed agent loads (bypass L1/L2, served by IF).
__global__ __launch_bounds__(NT, 1) void lstm_persist(Params p) {
    __shared__ float wx_lds[DD * 33];        // 66 KB: W_x slice, [k][c] pad-33
    __shared__ float hs[GBATCH * HH];        // 32 KB: h_{t-1}, 16 batches
    __shared__ float xs[GBATCH * DD];        // 32 KB: x_t, 16 batches
    __shared__ float part[GBATCH * 8 * 33];  // 16.9 KB: partials [bb][spair][33(c)]

    const int bid  = blockIdx.x;
    // XCD-pair swizzle (XCD assumed = bid & 7)
    const int g    = (bid & 7) >> 1;               // group 0..3 -> XCDs {2g,2g+1}
    const int k    = ((bid >> 3) << 1) | (bid & 1); // block-in-group 0..63
    const int tid  = threadIdx.x;
    const int c    = tid & 31;             // col 0..31
    const int s    = tid >> 5;             // K-slice 0..15
    const int gate = c >> 3;
    const int jcol = k * 8 + (c & 7);      // weight-matrix column
    const int b0   = g * GBATCH;
    const int kb   = s * 32;               // K-slice start (32 rows/thread)

    // ---- one-time: W_x slice (32 cols x 512 rows) into LDS, [k][c] ----
    for (int idx = tid; idx < 32 * DD; idx += NT) {
        int cc = idx & 31;
        int kk = idx >> 5;
        int gg = cc >> 3;
        int jc = k * 8 + (cc & 7);
        wx_lds[kk * 33 + cc] = p.Wx[gg][kk * HH + jc];
    }

    // ---- one-time: W_h slice into registers (32 floats) ----
    const float* WhG = p.Wh[gate];
    float4 wh4[8];
#pragma unroll
    for (int i = 0; i < 8; ++i) {
        int kk = kb + i * 4;
        wh4[i] = make_float4(WhG[(kk + 0) * HH + jcol], WhG[(kk + 1) * HH + jcol],
                             WhG[(kk + 2) * HH + jcol], WhG[(kk + 3) * HH + jcol]);
    }

    // Cell-update thread state (threads 0..127): (batch bbu, unit jju)
    const int bbu = tid >> 3;              // 0..15 (for tid<128)
    const int jju = tid & 7;
    const int ju  = k * 8 + jju;
    float cst = 0.0f;
    float bI = 0.f, bF = 0.f, bO = 0.f, bC = 0.f;
    if (tid < 128) {
        bI = p.bias[0][ju];
        bF = p.bias[1][ju];
        bO = p.bias[2][ju];
        bC = p.bias[3][ju];
    }

    unsigned int* ctrp = p.ctr + g * 64;
    const float4* xsrc = (const float4*)p.X;
    float4* hs4 = (float4*)hs;
    float4* xs4 = (float4*)xs;

    __syncthreads();   // wx_lds ready

    for (int t = 0; t < TT; ++t) {
        // ---- 1. stage x_t (no cross-block dependency): 4 float4/thread ----
#pragma unroll
        for (int u = 0; u < 4; ++u) {
            int idx = tid + u * NT;            // 0..2047 (float4 index)
            int b   = idx >> 7;                // 0..15
            int dd  = idx & 127;               // float4 within row
            xs4[b * 128 + dd] = xsrc[((size_t)(b0 + b) * TT + t) * 128 + dd];
        }
        __syncthreads();

        // ---- 2. x-projection FMAs, weights streamed from LDS.
        //      unroll 1: body = 4 ds_read_b32 + 16 ds_read_b128 + 64 FMA ----
        float acc[16];
#pragma unroll
        for (int bb = 0; bb < 16; ++bb) acc[bb] = 0.0f;
#pragma unroll 1
        for (int i4 = 0; i4 < 8; ++i4) {
            const int kk = kb + i4 * 4;
            const float w0 = wx_lds[(kk + 0) * 33 + c];
            const float w1 = wx_lds[(kk + 1) * 33 + c];
            const float w2 = wx_lds[(kk + 2) * 33 + c];
            const float w3 = wx_lds[(kk + 3) * 33 + c];
            const float4* xp = &xs4[s * 8 + i4];
#pragma unroll
            for (int bb = 0; bb < 16; ++bb) {
                float4 xv = xp[bb * 128];      // half-wave broadcast
                float a = acc[bb];
                a = fmaf(xv.x, w0, a);
                a = fmaf(xv.y, w1, a);
                a = fmaf(xv.z, w2, a);
                a = fmaf(xv.w, w3, a);
                acc[bb] = a;
            }
            __builtin_amdgcn_sched_barrier(0);
        }

        // ---- 3. wait for h_{t-1}: tid0-only relaxed spin (bypass load reads
        //      the IF directly — no fence, no cache invalidation) ----
        if (tid == 0) {
            const unsigned int need = (unsigned int)(GBLK * t);
            while (__hip_atomic_load(ctrp, __ATOMIC_RELAXED, __HIP_MEMORY_SCOPE_AGENT) < need) {
                __builtin_amdgcn_s_sleep(2);
            }
        }
        __syncthreads();

        // ---- 4. stage h_{t-1}: cache-bypassing (IF-coherent) loads,
        //      register-batched so all 16 loads are in flight at once ----
        {
            const float* hsrc = p.hbuf + (size_t)(t & 1) * BSZ * HH;
            float tmp[16];
#pragma unroll
            for (int u = 0; u < 16; ++u) {
                int idx = tid + u * NT;        // 0..8191
                int b   = idx >> 9;            // 0..15
                int d   = idx & 511;
                tmp[u] = __hip_atomic_load(&hsrc[(size_t)(b0 + b) * HH + d],
                                           __ATOMIC_RELAXED, __HIP_MEMORY_SCOPE_AGENT);
            }
#pragma unroll
            for (int u = 0; u < 16; ++u) {
                int idx = tid + u * NT;
                hs[idx] = tmp[u];
            }
        }
        __syncthreads();

        // ---- 5. recurrent FMAs, weights from registers. Full unroll is
        //      REQUIRED (wh4[] const indices); sched_barrier bounds the
        //      in-flight loads to one 16-b128 chunk ----
#pragma unroll
        for (int i4 = 0; i4 < 8; ++i4) {
            const float4 w = wh4[i4];
            const float4* hp = &hs4[s * 8 + i4];
#pragma unroll
            for (int bb = 0; bb < 16; ++bb) {
                float4 hv = hp[bb * 128];      // half-wave broadcast
                float a = acc[bb];
                a = fmaf(hv.x, w.x, a);
                a = fmaf(hv.y, w.y, a);
                a = fmaf(hv.z, w.z, a);
                a = fmaf(hv.w, w.w, a);
                acc[bb] = a;
            }
            __builtin_amdgcn_sched_barrier(0);
        }

        // ---- 6. pair-combine K-slices s and s^1 in-register (same wave:
        //      lanes 0..31 hold s even, 32..63 hold s odd), then write 8
        //      partial slices (stride 33: conflict-free) ----
#pragma unroll
        for (int bb = 0; bb < 16; ++bb)
            acc[bb] += __shfl_xor(acc[bb], 32);
        if ((s & 1) == 0) {
#pragma unroll
            for (int bb = 0; bb < 16; ++bb)
                part[(bb * 8 + (s >> 1)) * 33 + c] = acc[bb];
        }
        __syncthreads();

        // ---- 7. cell update ----
        if (tid < 128) {
            float v0 = bI, v1 = bF, v2 = bO, v3 = bC;
#pragma unroll
            for (int ss = 0; ss < 8; ++ss) {
                const float* pr = &part[(bbu * 8 + ss) * 33];
                v0 += pr[0 * 8 + jju];
                v1 += pr[1 * 8 + jju];
                v2 += pr[2 * 8 + jju];
                v3 += pr[3 * 8 + jju];
            }
            float I  = fast_sigmoid(v0);
            float F  = fast_sigmoid(v1);
            float O  = fast_sigmoid(v2);
            float Cd = fast_tanh(v3);
            cst = fmaf(F, cst, I * Cd);
            float h = O * fast_tanh(cst);
            // write-through to the IF (coherence point)
            __hip_atomic_store(&p.hbuf[(size_t)((t + 1) & 1) * BSZ * HH + (b0 + bbu) * HH + ju],
                               h, __ATOMIC_RELAXED, __HIP_MEMORY_SCOPE_AGENT);
            p.Y[((size_t)(b0 + bbu) * TT + t) * HH + ju] = h;
        }
        __syncthreads();   // drains vmcnt: h stores complete at the IF

        // ---- 8. publish: tid0 RELAXED add (ordering via the vmcnt drain) ----
        if (tid == 0) {
            __hip_atomic_fetch_add(ctrp, 1u, __ATOMIC_RELAXED, __HIP_MEMORY_SCOPE_AGENT);
        }
    }
}

extern "C" void kernel_launch(void* const* d_in, const int* in_sizes, int n_in,
                              void* d_out, int out_size, void* d_ws, size_t ws_size,
                              hipStream_t stream) {
    Params p;
    p.X       = (const float*)d_in[0];
    p.Wx[0]   = (const float*)d_in[1];
    p.Wh[0]   = (const float*)d_in[2];
    p.bias[0] = (const float*)d_in[3];
    p.Wx[1]   = (const float*)d_in[4];
    p.Wh[1]   = (const float*)d_in[5];
    p.bias[1] = (const float*)d_in[6];
    p.Wx[2]   = (const float*)d_in[7];
    p.Wh[2]   = (const float*)d_in[8];
    p.bias[2] = (const float*)d_in[9];
    p.Wx[3]   = (const float*)d_in[10];
    p.Wh[3]   = (const float*)d_in[11];
    p.bias[3] = (const float*)d_in[12];
    p.Y       = (float*)d_out;
    p.hbuf    = (float*)d_ws;
    p.ctr     = (unsigned int*)((char*)d_ws + (size_t)2 * BSZ * HH * sizeof(float));

    // ws is poisoned 0xAA before every timed launch: zero h0 double-buffer + counters
    init_ws<<<64, 256, 0, stream>>>(p.hbuf, p.ctr);

    lstm_persist<<<dim3(256), dim3(NT), 0, stream>>>(p);
}